// Round 2
// baseline (312.468 us; speedup 1.0000x reference)
//
#include <hip/hip_runtime.h>

// NSA compression attention fwd, MI355X/gfx950.  R5.
// R4 post-mortem: occupancy 18->29% bought nothing -> bottleneck is the
// phase-serial WG lifecycle (HBM idles during compute, compute idles during
// loads), not residency.  R5 restructures:
//  - K AND V^T staged ONCE per WG (69.6 KB LDS), then read-only ->
//    ONE barrier total, none in the main loop;
//  - 512-thread WGs (8 waves), 512 WGs = 2/CU resident, 16 waves/CU;
//  - each wave independently processes 2 strips of 32 query rows,
//    bx in {b, 31-b} -> per-wave cost constant (uniform, no tail);
//  - waves drift out of phase -> q-loads of some waves overlap MFMA/softmax
//    of others, no explicit pipelining needed;
//  - finer causal skip: nvmax = 4*bx + qq + 1 per 32-row strip.

#define Zc 4
#define Hc 16
#define Gc 4
#define Sc 4096
#define NBc 128
#define Dc 128
#define VST 136

typedef __attribute__((ext_vector_type(8))) short short8;   // 8 bf16
typedef __attribute__((ext_vector_type(4))) float float4v;  // 4 fp32

__device__ inline unsigned pk2bf(float a, float b) {
    union { float f; unsigned u; } x, y; x.f = a; y.f = b;
    return __builtin_amdgcn_perm(y.u + 0x8000u, x.u + 0x8000u, 0x07060302u);
}
__device__ inline short8 mkfrag(float4v f0, float4v f1) {
    union { short8 v; unsigned d[4]; } u;
    u.d[0] = pk2bf(f0[0], f0[1]);
    u.d[1] = pk2bf(f0[2], f0[3]);
    u.d[2] = pk2bf(f1[0], f1[1]);
    u.d[3] = pk2bf(f1[2], f1[3]);
    return u.v;
}

__global__ __launch_bounds__(512, 4)   // 4 waves/SIMD = 16 waves/CU = 2 WG/CU
void nsa_fwd(const float* __restrict__ q, const float* __restrict__ kb,
             const float* __restrict__ vb, float* __restrict__ out) {
    __shared__ __align__(16) short Ksh[NBc * VST];   // 34816 B
    __shared__ __align__(16) short Vt[Dc * VST];     // 34816 B -> 69632 total

    const int wgp  = blockIdx.x;                 // 0..31: WG within (z,g) pair
    const int g    = blockIdx.y, z = blockIdx.z;
    const int tid  = threadIdx.x;
    const int wq   = tid >> 6;                   // wave 0..7
    const int lane = tid & 63;
    const int l16  = lane & 15;
    const int quad = lane >> 4;

    // per-wave strip assignment: W in [0,256) per pair
    const int W     = wgp * 8 + wq;
    const int b     = W & 15;                    // bx seed
    const int h_loc = (W >> 4) & 3;
    const int qq    = (W >> 6) & 3;              // 32-row quarter within 128-tile
    const int h     = g * 4 + h_loc;

    // ---- stage K -> LDS bf16, coalesced (once per WG) ----
    const float* ksrc = kb + (size_t)(z * Gc + g) * NBc * Dc;
    #pragma unroll
    for (int it = 0; it < 4; it++) {
        int i = it * 512 + tid;
        int n = i >> 4, c8 = i & 15;             // row, 8-float chunk
        const float* s = ksrc + (size_t)n * Dc + c8 * 8;
        float4v f0 = *(const float4v*)s, f1 = *(const float4v*)(s + 4);
        *(short8*)(Ksh + n * VST + c8 * 8) = mkfrag(f0, f1);
    }
    // ---- stage V^T -> LDS bf16, column-pair packed (once per WG) ----
    {
        const float* vsrc = vb + (size_t)(z * Gc + g) * NBc * Dc;
        const int n2 = lane * 2;
        #pragma unroll
        for (int it = 0; it < 4; it++) {
            const int c = it * 8 + wq;           // d-chunk of 4, wave-uniform
            float4v fa = *(const float4v*)(vsrc + (size_t)n2 * Dc + c * 4);
            float4v fb = *(const float4v*)(vsrc + (size_t)(n2 + 1) * Dc + c * 4);
            #pragma unroll
            for (int k2 = 0; k2 < 4; k2++)
                *(unsigned*)(Vt + (c * 4 + k2) * VST + n2) = pk2bf(fa[k2], fb[k2]);
        }
    }

    __syncthreads();   // the ONLY barrier; LDS read-only afterwards

    const float sm = 0.08838834764831845f;       // 1/sqrt(128)

    for (int si = 0; si < 2; si++) {
        const int bx = si ? (31 - b) : b;
        const int m0 = bx * 128 + qq * 32;
        const int nvmax   = 4 * bx + qq + 1;     // max valid blocks this strip
        const int c_max   = (nvmax + 15) >> 4;
        const int kbi_max = (nvmax + 31) >> 5;

        // ---- q loads + bf16 frags, sm_scale folded ----
        const float* qbase = q + ((size_t)(z * Hc + h) * Sc + m0) * Dc;
        short8 qf[4][2];
        #pragma unroll
        for (int dk = 0; dk < 4; dk++)
            #pragma unroll
            for (int t = 0; t < 2; t++) {
                const float* s = qbase + (size_t)(t * 16 + l16) * Dc + dk * 32 + quad * 8;
                float4v f0 = *(const float4v*)s;
                float4v f1 = *(const float4v*)(s + 4);
                qf[dk][t] = mkfrag(f0 * sm, f1 * sm);
            }

        // ---- GEMM1: S^T = K * Q^T ----
        float4v acc[8][2];   // col=l16=query, row=quad*4+r = block j (within c*16)
        #pragma unroll
        for (int c = 0; c < 8; c++)
            #pragma unroll
            for (int t = 0; t < 2; t++) acc[c][t] = (float4v)0.f;

        #pragma unroll
        for (int dk = 0; dk < 4; dk++)
            #pragma unroll
            for (int c = 0; c < 8; c++)
                if (c < c_max) {
                    short8 a = *(const short8*)(Ksh + (c * 16 + l16) * VST + dk * 32 + quad * 8);
                    acc[c][0] = __builtin_amdgcn_mfma_f32_16x16x32_bf16(a, qf[dk][0], acc[c][0], 0, 0, 0);
                    acc[c][1] = __builtin_amdgcn_mfma_f32_16x16x32_bf16(a, qf[dk][1], acc[c][1], 0, 0, 0);
                }

        // ---- softmax over blocks + normalize + pack bf16 ----
        unsigned Ppk[8][2][2];
        #pragma unroll
        for (int c = 0; c < 8; c++)
            #pragma unroll
            for (int t = 0; t < 2; t++) { Ppk[c][t][0] = 0u; Ppk[c][t][1] = 0u; }

        #pragma unroll
        for (int t = 0; t < 2; t++) {
            const int mg = m0 + t * 16 + l16;
            int nv = (mg + 1) >> 5; if (nv > NBc) nv = NBc;
            float mx = -1e30f;
            #pragma unroll
            for (int c = 0; c < 8; c++)
                if (c < c_max)
                    #pragma unroll
                    for (int r = 0; r < 4; r++) {
                        const int j = c * 16 + quad * 4 + r;
                        float s = acc[c][t][r];
                        s = (j < nv) ? s : -1e30f;
                        acc[c][t][r] = s;
                        mx = fmaxf(mx, s);
                    }
            mx = fmaxf(mx, __shfl_xor(mx, 16, 64));
            mx = fmaxf(mx, __shfl_xor(mx, 32, 64));
            float ls = 0.f;
            #pragma unroll
            for (int c = 0; c < 8; c++)
                if (c < c_max)
                    #pragma unroll
                    for (int r = 0; r < 4; r++) {
                        float s = acc[c][t][r];
                        float p = (s > -1e29f) ? __expf(s - mx) : 0.f;
                        acc[c][t][r] = p;
                        ls += p;
                    }
            ls += __shfl_xor(ls, 16, 64);
            ls += __shfl_xor(ls, 32, 64);
            const float inv = (ls > 0.f) ? 1.f / ls : 0.f;
            #pragma unroll
            for (int c = 0; c < 8; c++)
                if (c < c_max) {
                    Ppk[c][t][0] = pk2bf(acc[c][t][0] * inv, acc[c][t][1] * inv);
                    Ppk[c][t][1] = pk2bf(acc[c][t][2] * inv, acc[c][t][3] * inv);
                }
        }

        // ---- GEMM2: O = P * V.  A = P via quad-shuffle; B = V^T LDS ----
        float4v oacc[8][2];
        #pragma unroll
        for (int c = 0; c < 8; c++)
            #pragma unroll
            for (int t = 0; t < 2; t++) oacc[c][t] = (float4v)0.f;

        const int s0 = (((2 * quad) & 3) << 4) | l16;
        const int s1 = (((2 * quad + 1) & 3) << 4) | l16;
        const bool hi = (quad >= 2);

        #pragma unroll
        for (int kbi = 0; kbi < 4; kbi++)
            if (kbi < kbi_max) {
                short8 ap[2];
                #pragma unroll
                for (int t = 0; t < 2; t++) {
                    const int c1 = 2 * kbi;
                    unsigned w0a = (unsigned)__shfl((int)Ppk[c1    ][t][0], s0, 64);
                    unsigned w0b = (unsigned)__shfl((int)Ppk[c1 + 1][t][0], s0, 64);
                    unsigned w1a = (unsigned)__shfl((int)Ppk[c1    ][t][1], s0, 64);
                    unsigned w1b = (unsigned)__shfl((int)Ppk[c1 + 1][t][1], s0, 64);
                    unsigned w2a = (unsigned)__shfl((int)Ppk[c1    ][t][0], s1, 64);
                    unsigned w2b = (unsigned)__shfl((int)Ppk[c1 + 1][t][0], s1, 64);
                    unsigned w3a = (unsigned)__shfl((int)Ppk[c1    ][t][1], s1, 64);
                    unsigned w3b = (unsigned)__shfl((int)Ppk[c1 + 1][t][1], s1, 64);
                    union { short8 v; unsigned d[4]; } u;
                    u.d[0] = hi ? w0b : w0a;
                    u.d[1] = hi ? w1b : w1a;
                    u.d[2] = hi ? w2b : w2a;
                    u.d[3] = hi ? w3b : w3a;
                    ap[t] = u.v;
                }
                #pragma unroll
                for (int c = 0; c < 8; c++) {
                    short8 bv = *(const short8*)(Vt + (c * 16 + l16) * VST + kbi * 32 + quad * 8);
                    #pragma unroll
                    for (int t = 0; t < 2; t++)
                        oacc[c][t] = __builtin_amdgcn_mfma_f32_16x16x32_bf16(ap[t], bv, oacc[c][t], 0, 0, 0);
                }
            }

        // ---- store (P pre-normalized): row=quad*4+rr = query, col=l16 = dv ----
        float* obase = out + ((size_t)(z * Hc + h) * Sc + m0) * Dc;
        #pragma unroll
        for (int t = 0; t < 2; t++)
            #pragma unroll
            for (int rr = 0; rr < 4; rr++) {
                const int row = t * 16 + quad * 4 + rr;
                #pragma unroll
                for (int c = 0; c < 8; c++)
                    obase[(size_t)row * Dc + c * 16 + l16] = oacc[c][t][rr];
            }
    }
}

extern "C" void kernel_launch(void* const* d_in, const int* in_sizes, int n_in,
                              void* d_out, int out_size, void* d_ws, size_t ws_size,
                              hipStream_t stream) {
    const float* q  = (const float*)d_in[0];
    const float* kb = (const float*)d_in[1];
    const float* vb = (const float*)d_in[2];
    // d_in[3] = block_ends; analytic: block j valid iff j < (m+1)>>5
    float* out = (float*)d_out;
    dim3 grid(32, Gc, Zc);                       // 512 WGs = 2/CU, one round
    nsa_fwd<<<grid, dim3(512), 0, stream>>>(q, kb, vb, out);
}

// Round 3
// 249.231 us; speedup vs baseline: 1.2537x; 1.2537x over previous
//
#include <hip/hip_runtime.h>

// NSA compression attention fwd, MI355X/gfx950.  R6.
// R5 post-mortem: decorrelated strips doubled HBM traffic (WRITE 131->252MB)
// -> reverted.  R4 post-mortem: occupancy is not the lever; phase-serial
// duty cycle is.  R6 = R4's exact tile/store/stage structure (verified
// traffic), but 2 tiles {b, 31-b} per WG with a software pipeline:
//   [q0 + K stage(shared, guarded)] bar1
//   [q1 issue] GEMM1(t0) softmax(t0)         <- q1 HBM under compute
//   [qf1 pack, V->reg issue] GEMM1(t1)       <- V HBM under compute (T14)
//   bar2 [V ds_write + softmax(t1)]          <- VALU under ds_write
//   bar3 GEMM2(t0)+store(t0) GEMM2(t1)+store(t1)  <- stores under compute
// K staged ONCE for both tiles (-27% staging), per-wave causal bound
// nvmax = 4*bx + wq + 1.  LDS 34.8 KB single buffer, launch_bounds(256,2).

#define Zc 4
#define Hc 16
#define Gc 4
#define Sc 4096
#define NBc 128
#define Dc 128
#define VST 136

typedef __attribute__((ext_vector_type(8))) short short8;   // 8 bf16
typedef __attribute__((ext_vector_type(4))) float float4v;  // 4 fp32

__device__ inline unsigned pk2bf(float a, float b) {
    union { float f; unsigned u; } x, y; x.f = a; y.f = b;
    return __builtin_amdgcn_perm(y.u + 0x8000u, x.u + 0x8000u, 0x07060302u);
}
__device__ inline short8 mkfrag(float4v f0, float4v f1) {
    union { short8 v; unsigned d[4]; } u;
    u.d[0] = pk2bf(f0[0], f0[1]);
    u.d[1] = pk2bf(f0[2], f0[3]);
    u.d[2] = pk2bf(f1[0], f1[1]);
    u.d[3] = pk2bf(f1[2], f1[3]);
    return u.v;
}

__device__ inline void do_gemm1(const short* __restrict__ Ksh, short8 (&qf)[4][2],
                                float4v (&acc)[8][2], int c_max, int l16, int quad) {
    #pragma unroll
    for (int c = 0; c < 8; c++)
        #pragma unroll
        for (int t = 0; t < 2; t++) acc[c][t] = (float4v)0.f;
    #pragma unroll
    for (int dk = 0; dk < 4; dk++)
        #pragma unroll
        for (int c = 0; c < 8; c++)
            if (c < c_max) {
                short8 a = *(const short8*)(Ksh + (c * 16 + l16) * VST + dk * 32 + quad * 8);
                acc[c][0] = __builtin_amdgcn_mfma_f32_16x16x32_bf16(a, qf[dk][0], acc[c][0], 0, 0, 0);
                acc[c][1] = __builtin_amdgcn_mfma_f32_16x16x32_bf16(a, qf[dk][1], acc[c][1], 0, 0, 0);
            }
}

__device__ inline void do_softmax(float4v (&acc)[8][2], unsigned (&Ppk)[8][2][2],
                                  int m0, int c_max, int l16, int quad) {
    #pragma unroll
    for (int c = 0; c < 8; c++)
        #pragma unroll
        for (int t = 0; t < 2; t++) { Ppk[c][t][0] = 0u; Ppk[c][t][1] = 0u; }
    #pragma unroll
    for (int t = 0; t < 2; t++) {
        const int mg = m0 + t * 16 + l16;
        int nv = (mg + 1) >> 5; if (nv > NBc) nv = NBc;
        float mx = -1e30f;
        #pragma unroll
        for (int c = 0; c < 8; c++)
            if (c < c_max)
                #pragma unroll
                for (int r = 0; r < 4; r++) {
                    const int j = c * 16 + quad * 4 + r;
                    float s = acc[c][t][r];
                    s = (j < nv) ? s : -1e30f;
                    acc[c][t][r] = s;
                    mx = fmaxf(mx, s);
                }
        mx = fmaxf(mx, __shfl_xor(mx, 16, 64));
        mx = fmaxf(mx, __shfl_xor(mx, 32, 64));
        float ls = 0.f;
        #pragma unroll
        for (int c = 0; c < 8; c++)
            if (c < c_max)
                #pragma unroll
                for (int r = 0; r < 4; r++) {
                    float s = acc[c][t][r];
                    float p = (s > -1e29f) ? __expf(s - mx) : 0.f;
                    acc[c][t][r] = p;
                    ls += p;
                }
        ls += __shfl_xor(ls, 16, 64);
        ls += __shfl_xor(ls, 32, 64);
        const float inv = (ls > 0.f) ? 1.f / ls : 0.f;
        #pragma unroll
        for (int c = 0; c < 8; c++)
            if (c < c_max) {
                Ppk[c][t][0] = pk2bf(acc[c][t][0] * inv, acc[c][t][1] * inv);
                Ppk[c][t][1] = pk2bf(acc[c][t][2] * inv, acc[c][t][3] * inv);
            }
    }
}

__device__ inline void do_gemm2_store(const short* __restrict__ Vt, unsigned (&Ppk)[8][2][2],
                                      float* __restrict__ obase, int kbi_max,
                                      int l16, int quad) {
    float4v oacc[8][2];
    #pragma unroll
    for (int c = 0; c < 8; c++)
        #pragma unroll
        for (int t = 0; t < 2; t++) oacc[c][t] = (float4v)0.f;

    const int s0 = (((2 * quad) & 3) << 4) | l16;
    const int s1 = (((2 * quad + 1) & 3) << 4) | l16;
    const bool hi = (quad >= 2);

    #pragma unroll
    for (int kbi = 0; kbi < 4; kbi++)
        if (kbi < kbi_max) {
            short8 ap[2];
            #pragma unroll
            for (int t = 0; t < 2; t++) {
                const int c1 = 2 * kbi;
                unsigned w0a = (unsigned)__shfl((int)Ppk[c1    ][t][0], s0, 64);
                unsigned w0b = (unsigned)__shfl((int)Ppk[c1 + 1][t][0], s0, 64);
                unsigned w1a = (unsigned)__shfl((int)Ppk[c1    ][t][1], s0, 64);
                unsigned w1b = (unsigned)__shfl((int)Ppk[c1 + 1][t][1], s0, 64);
                unsigned w2a = (unsigned)__shfl((int)Ppk[c1    ][t][0], s1, 64);
                unsigned w2b = (unsigned)__shfl((int)Ppk[c1 + 1][t][0], s1, 64);
                unsigned w3a = (unsigned)__shfl((int)Ppk[c1    ][t][1], s1, 64);
                unsigned w3b = (unsigned)__shfl((int)Ppk[c1 + 1][t][1], s1, 64);
                union { short8 v; unsigned d[4]; } u;
                u.d[0] = hi ? w0b : w0a;
                u.d[1] = hi ? w1b : w1a;
                u.d[2] = hi ? w2b : w2a;
                u.d[3] = hi ? w3b : w3a;
                ap[t] = u.v;
            }
            #pragma unroll
            for (int c = 0; c < 8; c++) {
                short8 bv = *(const short8*)(Vt + (c * 16 + l16) * VST + kbi * 32 + quad * 8);
                #pragma unroll
                for (int t = 0; t < 2; t++)
                    oacc[c][t] = __builtin_amdgcn_mfma_f32_16x16x32_bf16(ap[t], bv, oacc[c][t], 0, 0, 0);
            }
        }

    #pragma unroll
    for (int t = 0; t < 2; t++)
        #pragma unroll
        for (int rr = 0; rr < 4; rr++) {
            const int row = t * 16 + quad * 4 + rr;
            #pragma unroll
            for (int c = 0; c < 8; c++)
                obase[(size_t)row * Dc + c * 16 + l16] = oacc[c][t][rr];
        }
}

__global__ __launch_bounds__(256, 2)
void nsa_fwd(const float* __restrict__ q, const float* __restrict__ kb,
             const float* __restrict__ vb, float* __restrict__ out) {
    // One buffer, two lives: K rows [n][d] for both GEMM1s, then V^T [d][n].
    __shared__ __align__(16) short KV[NBc * VST];   // 34816 B

    const int b    = blockIdx.x;               // 0..15 -> tiles {b, 31-b}
    const int h    = blockIdx.y, z = blockIdx.z, g = h >> 2;
    const int tid  = threadIdx.x;
    const int wq   = tid >> 6;
    const int lane = tid & 63;
    const int l16  = lane & 15;
    const int quad = lane >> 4;

    const int bx0 = b, bx1 = 31 - b;
    const int nv0 = 4 * bx0 + wq + 1;          // per-wave causal bounds
    const int nv1 = 4 * bx1 + wq + 1;
    const int cmax0 = (nv0 + 15) >> 4, kbi0 = (nv0 + 31) >> 5;
    const int cmax1 = (nv1 + 15) >> 4, kbi1 = (nv1 + 31) >> 5;
    const int nv_hi  = 4 * bx1 + 4;            // staging must cover tile bx1
    const int cst    = (nv_hi + 15) >> 4;      // K-stage 16-row iters (WG-uniform)
    const int nstage = ((nv_hi + 31) >> 5) << 5;

    const int m0_0 = bx0 * 128 + wq * 32;
    const int m0_1 = bx1 * 128 + wq * 32;
    const float sm = 0.08838834764831845f;     // 1/sqrt(128)

    // ---- phase 1: q0 loads + K stage (once, for both tiles) ----
    const float* qb0 = q + ((size_t)(z * Hc + h) * Sc + m0_0) * Dc;
    float4v q0raw[4][2][2];
    #pragma unroll
    for (int dk = 0; dk < 4; dk++)
        #pragma unroll
        for (int t = 0; t < 2; t++) {
            const float* s = qb0 + (size_t)(t * 16 + l16) * Dc + dk * 32 + quad * 8;
            q0raw[dk][t][0] = *(const float4v*)s;
            q0raw[dk][t][1] = *(const float4v*)(s + 4);
        }

    const float* ksrc = kb + (size_t)(z * Gc + g) * NBc * Dc;
    #pragma unroll
    for (int it = 0; it < 8; it++)
        if (it < cst) {                        // WG-uniform guard
            int i = it * 256 + tid;
            int n = i >> 4, c8 = i & 15;
            const float* s = ksrc + (size_t)n * Dc + c8 * 8;
            float4v f0 = *(const float4v*)s, f1 = *(const float4v*)(s + 4);
            *(short8*)(KV + n * VST + c8 * 8) = mkfrag(f0, f1);
        }

    short8 qf[4][2];
    #pragma unroll
    for (int dk = 0; dk < 4; dk++)
        #pragma unroll
        for (int t = 0; t < 2; t++)
            qf[dk][t] = mkfrag(q0raw[dk][t][0] * sm, q0raw[dk][t][1] * sm);

    __syncthreads();   // bar1: K visible

    // ---- phase 2: issue q1 loads, then tile0 GEMM1 + softmax ----
    const float* qb1 = q + ((size_t)(z * Hc + h) * Sc + m0_1) * Dc;
    float4v q1raw[4][2][2];
    #pragma unroll
    for (int dk = 0; dk < 4; dk++)
        #pragma unroll
        for (int t = 0; t < 2; t++) {
            const float* s = qb1 + (size_t)(t * 16 + l16) * Dc + dk * 32 + quad * 8;
            q1raw[dk][t][0] = *(const float4v*)s;
            q1raw[dk][t][1] = *(const float4v*)(s + 4);
        }

    float4v acc[8][2];
    unsigned Ppk0[8][2][2], Ppk1[8][2][2];

    do_gemm1(KV, qf, acc, cmax0, l16, quad);
    do_softmax(acc, Ppk0, m0_0, cmax0, l16, quad);

    // ---- phase 3: pack qf1, issue V->reg loads, tile1 GEMM1 ----
    #pragma unroll
    for (int dk = 0; dk < 4; dk++)
        #pragma unroll
        for (int t = 0; t < 2; t++)
            qf[dk][t] = mkfrag(q1raw[dk][t][0] * sm, q1raw[dk][t][1] * sm);

    const float* vsrc = vb + (size_t)(z * Gc + g) * NBc * Dc;
    const int n2 = lane * 2;                   // column pair
    const bool vact = (n2 < nstage);
    float4v vraw[8][2];
    #pragma unroll
    for (int it = 0; it < 8; it++) {
        const int c = it * 4 + wq;             // d-chunk of 4, wave-uniform
        if (vact) {
            vraw[it][0] = *(const float4v*)(vsrc + (size_t)n2 * Dc + c * 4);
            vraw[it][1] = *(const float4v*)(vsrc + (size_t)(n2 + 1) * Dc + c * 4);
        }
    }

    do_gemm1(KV, qf, acc, cmax1, l16, quad);   // V loads in flight underneath

    __syncthreads();   // bar2: all K reads done; safe to overwrite

    // ---- phase 4: V ds_write (from regs) + tile1 softmax ----
    #pragma unroll
    for (int it = 0; it < 8; it++) {
        const int c = it * 4 + wq;
        if (vact) {
            #pragma unroll
            for (int k2 = 0; k2 < 4; k2++)
                *(unsigned*)(KV + (c * 4 + k2) * VST + n2) = pk2bf(vraw[it][0][k2], vraw[it][1][k2]);
        }
    }
    do_softmax(acc, Ppk1, m0_1, cmax1, l16, quad);

    __syncthreads();   // bar3: V^T visible

    // ---- phase 5: GEMM2 + store, t0 then t1 (t0 stores fly under t1) ----
    float* ob0 = out + ((size_t)(z * Hc + h) * Sc + m0_0) * Dc;
    float* ob1 = out + ((size_t)(z * Hc + h) * Sc + m0_1) * Dc;
    do_gemm2_store(KV, Ppk0, ob0, kbi0, l16, quad);
    do_gemm2_store(KV, Ppk1, ob1, kbi1, l16, quad);
}

extern "C" void kernel_launch(void* const* d_in, const int* in_sizes, int n_in,
                              void* d_out, int out_size, void* d_ws, size_t ws_size,
                              hipStream_t stream) {
    const float* q  = (const float*)d_in[0];
    const float* kb = (const float*)d_in[1];
    const float* vb = (const float*)d_in[2];
    // d_in[3] = block_ends; analytic: block j valid iff j < (m+1)>>5
    float* out = (float*)d_out;
    dim3 grid(16, Hc, Zc);                     // 1024 WGs, 2 tiles each
    nsa_fwd<<<grid, dim3(256), 0, stream>>>(q, kb, vb, out);
}